// Round 3
// baseline (5335.706 us; speedup 1.0000x reference)
//
#include <hip/hip_runtime.h>

// Round 3: latency-bound fix for the MLP kernels.
//  - Weight/bias pointers pinned into VGPRs (empty asm) -> vector loads on
//    vmcnt, so lgkmcnt stays pure-DS (no SMEM/DS out-of-order drains).
//  - Intra-wave k-split (4-way edge, 2-way unary/update) with __shfl_xor
//    butterfly combine -> no barriers, small per-thread LDS t (stride 33,
//    bank-conflict-free), 16 waves/CU target occupancy.

#define E 64
#define TWO_E 128

__device__ __forceinline__ const float* vpin(const float* p) {
  unsigned long long u = (unsigned long long)p;
  asm("" : "+v"(u));          // force VGPR; breaks uniformity proof -> vector loads
  return (const float*)u;
}

// acc[0..31] += xu * w[0..31]   (w = 8 consecutive float4, imm-offset loads)
__device__ __forceinline__ void fma32(float (&acc)[32], float xu, const float* w) {
  const float4* wp = (const float4*)w;
  #pragma unroll
  for (int i = 0; i < 8; ++i) {
    float4 wv = wp[i];
    acc[4*i+0] = fmaf(xu, wv.x, acc[4*i+0]);
    acc[4*i+1] = fmaf(xu, wv.y, acc[4*i+1]);
    acc[4*i+2] = fmaf(xu, wv.z, acc[4*i+2]);
    acc[4*i+3] = fmaf(xu, wv.w, acc[4*i+3]);
  }
}

__device__ __forceinline__ void load32(float (&acc)[32], const float* p) {
  const float4* p4 = (const float4*)p;
  #pragma unroll
  for (int i = 0; i < 8; ++i) {
    float4 v = p4[i];
    acc[4*i+0]=v.x; acc[4*i+1]=v.y; acc[4*i+2]=v.z; acc[4*i+3]=v.w;
  }
}

// ---------------- zero ----------------
__global__ void k_zero(float4* __restrict__ p, int n4) {
  int i = blockIdx.x * blockDim.x + threadIdx.x;
  if (i < n4) p[i] = make_float4(0.f, 0.f, 0.f, 0.f);
}

// ---------------- CSR build (once per launch) ----------------
__global__ void k_count(const int* __restrict__ rel_u, const int* __restrict__ rel_e,
                        int* __restrict__ cnt, int mu, int M) {
  int m = blockIdx.x * blockDim.x + threadIdx.x;
  if (m >= M) return;
  int d = (m < mu) ? rel_u[m] : rel_e[m - mu];
  atomicAdd(&cnt[d], 1);
}

__global__ void __launch_bounds__(1024) k_scan(const int* __restrict__ cnt,
                                               int* __restrict__ startp, int nn, int M) {
  __shared__ int ls[1024];
  int t = threadIdx.x;
  const int C = 49;
  int c0 = t * C, c1 = min(c0 + C, nn);
  int s = 0;
  for (int i = c0; i < c1; ++i) s += cnt[i];
  ls[t] = s;
  __syncthreads();
  for (int off = 1; off < 1024; off <<= 1) {
    int v = (t >= off) ? ls[t - off] : 0;
    __syncthreads();
    ls[t] += v;
    __syncthreads();
  }
  int run = (t > 0) ? ls[t - 1] : 0;
  for (int i = c0; i < c1; ++i) { startp[i] = run; run += cnt[i]; }
  if (t == 1023) startp[nn] = M;
}

__global__ void k_copyint(const int* __restrict__ a, int* __restrict__ b, int n) {
  int i = blockIdx.x * blockDim.x + threadIdx.x;
  if (i < n) b[i] = a[i];
}

__global__ void k_fill(const int* __restrict__ rel_u, const int* __restrict__ rel_e,
                       int* __restrict__ cursor, int* __restrict__ idx, int mu, int M) {
  int m = blockIdx.x * blockDim.x + threadIdx.x;
  if (m >= M) return;
  int d = (m < mu) ? rel_u[m] : rel_e[m - mu];
  int p = atomicAdd(&cursor[d], 1);
  idx[p] = m;
}

// -------- unary messages: msgbuf[a] = MLP(h[rel_u[a]]). 2-way hidden/k split.
// lane = (q<<5)|aidx ; q=0/1 owns hidden half; combine layer-2 via shfl_xor(32).
__global__ void __launch_bounds__(256, 4) k_unary(
    const int* __restrict__ rel_u, const float* __restrict__ h,
    const float* __restrict__ W1_, const float* __restrict__ b1_,
    const float* __restrict__ W2_, const float* __restrict__ b2_,
    float* __restrict__ msgbuf, int mu)
{
  __shared__ float tl[256 * 33];          // 33,792 B
  const int tid = threadIdx.x;
  const int lane = tid & 63;
  const int q = lane >> 5;                // hidden half 0/1
  const int a = blockIdx.x * 128 + (tid >> 6) * 32 + (lane & 31);
  if (a >= mu) return;                    // partner lanes share `a` -> shfl safe
  const float* W1 = vpin(W1_);
  const float* W2 = vpin(W2_);
  const float* b1 = vpin(b1_);
  const float* b2 = vpin(b2_);

  const int idx = rel_u[a];
  const float4* x4 = (const float4*)(h + (size_t)idx * E);

  // layer 1: this lane computes hidden[q*32 .. q*32+32)
  float acc[32];
  load32(acc, b1 + q * 32);
  const float* wrow = W1 + q * 32;        // row stride E
  #pragma unroll 2
  for (int k4 = 0; k4 < 16; ++k4) {
    float4 xv = x4[k4];
    fma32(acc, xv.x, wrow);
    fma32(acc, xv.y, wrow + E);
    fma32(acc, xv.z, wrow + 2 * E);
    fma32(acc, xv.w, wrow + 3 * E);
    wrow += 4 * E;
  }
  float* tme = &tl[tid * 33];
  #pragma unroll
  for (int i = 0; i < 32; ++i) tme[i] = fmaxf(acc[i], 0.f);

  // layer 2: 2 chunks of 32 outputs; partial over own k-half; combine
  #pragma unroll 1
  for (int c = 0; c < 2; ++c) {
    float o[32];
    #pragma unroll
    for (int i = 0; i < 32; ++i) o[i] = 0.f;
    const float* w2r = W2 + (q * 32) * E + c * 32;
    #pragma unroll 2
    for (int k = 0; k < 32; ++k) {
      float tk = tme[k];
      fma32(o, tk, w2r);
      w2r += E;
    }
    #pragma unroll
    for (int i = 0; i < 32; ++i) o[i] += __shfl_xor(o[i], 32, 64);
    if (q == c) {
      const float4* bp = (const float4*)(b2 + c * 32);
      float4* mp = (float4*)(msgbuf + (size_t)a * E + c * 32);
      #pragma unroll
      for (int i = 0; i < 8; ++i) {
        float4 bv = bp[i];
        mp[i] = make_float4(o[4*i]+bv.x, o[4*i+1]+bv.y, o[4*i+2]+bv.z, o[4*i+3]+bv.w);
      }
    }
  }
}

// -------- edge messages: 4-way split. lane = (q<<4)|eidx; q owns hidden
// quarter (layer1) == k quarter (layer2). Butterfly shfl_xor(16),(32).
// out[0:64] -> slot mu+2e (->s), out[64:128] -> slot mu+2e+1 (->d).
__global__ void __launch_bounds__(256, 4) k_edge(
    const int* __restrict__ rel_e, const float* __restrict__ h,
    const float* __restrict__ W1_, const float* __restrict__ b1_,
    const float* __restrict__ W2_, const float* __restrict__ b2_,
    float* __restrict__ msgbuf, int mu, int me)
{
  __shared__ float tl[256 * 33];
  const int tid = threadIdx.x;
  const int lane = tid & 63;
  const int q = lane >> 4;                // quarter 0..3
  const int e = blockIdx.x * 64 + (tid >> 6) * 16 + (lane & 15);
  if (e >= me) return;                    // partner lanes share `e`
  const float* W1 = vpin(W1_);
  const float* W2 = vpin(W2_);
  const float* b1 = vpin(b1_);
  const float* b2 = vpin(b2_);

  const int s = rel_e[2 * e], d = rel_e[2 * e + 1];
  const float4* xs4 = (const float4*)(h + (size_t)s * E);
  const float4* xd4 = (const float4*)(h + (size_t)d * E);

  // layer 1: hidden[q*32 .. q*32+32) from 128-wide [h[s], h[d]]
  float acc[32];
  load32(acc, b1 + q * 32);
  const float* wrow = W1 + q * 32;        // row stride TWO_E
  #pragma unroll 2
  for (int k4 = 0; k4 < 16; ++k4) {
    float4 xv = xs4[k4];
    fma32(acc, xv.x, wrow);
    fma32(acc, xv.y, wrow + TWO_E);
    fma32(acc, xv.z, wrow + 2 * TWO_E);
    fma32(acc, xv.w, wrow + 3 * TWO_E);
    wrow += 4 * TWO_E;
  }
  #pragma unroll 2
  for (int k4 = 0; k4 < 16; ++k4) {
    float4 xv = xd4[k4];
    fma32(acc, xv.x, wrow);
    fma32(acc, xv.y, wrow + TWO_E);
    fma32(acc, xv.z, wrow + 2 * TWO_E);
    fma32(acc, xv.w, wrow + 3 * TWO_E);
    wrow += 4 * TWO_E;
  }
  float* tme = &tl[tid * 33];
  #pragma unroll
  for (int i = 0; i < 32; ++i) tme[i] = fmaxf(acc[i], 0.f);

  // layer 2: 4 chunks of 32 outputs; partial over own k-quarter
  #pragma unroll 1
  for (int c = 0; c < 4; ++c) {
    float o[32];
    #pragma unroll
    for (int i = 0; i < 32; ++i) o[i] = 0.f;
    const float* w2r = W2 + (q * 32) * TWO_E + c * 32;
    #pragma unroll 2
    for (int k = 0; k < 32; ++k) {
      float tk = tme[k];
      fma32(o, tk, w2r);
      w2r += TWO_E;
    }
    #pragma unroll
    for (int i = 0; i < 32; ++i) {
      float v = o[i];
      v += __shfl_xor(v, 16, 64);
      v += __shfl_xor(v, 32, 64);
      o[i] = v;
    }
    if (q == c) {
      const float4* bp = (const float4*)(b2 + c * 32);
      size_t slot = (size_t)mu + 2 * (size_t)e + (c >> 1);
      float4* mp = (float4*)(msgbuf + slot * E + (c & 1) * 32);
      #pragma unroll
      for (int i = 0; i < 8; ++i) {
        float4 bv = bp[i];
        mp[i] = make_float4(o[4*i]+bv.x, o[4*i+1]+bv.y, o[4*i+2]+bv.z, o[4*i+3]+bv.w);
      }
    }
  }
}

// ---------------- gather: agg[n] = sum msgbuf[idx[start[n]..start[n+1])] ----
__global__ void __launch_bounds__(256) k_gather(
    const float* __restrict__ msgbuf, const int* __restrict__ idx,
    const int* __restrict__ startp, float* __restrict__ agg, int nn)
{
  int wave = threadIdx.x >> 6;
  int j = threadIdx.x & 63;
  int n = blockIdx.x * 4 + wave;
  if (n >= nn) return;
  int s0 = startp[n], s1 = startp[n + 1];
  float v = 0.f;
  for (int i = s0; i < s1; ++i) {
    int m = idx[i];
    v += msgbuf[(size_t)m * E + j];
  }
  agg[(size_t)n * E + j] = v;
}

// ---------------- readout: gsum[g] = sum_{n in g} h[n] ----------------
__global__ void k_readout(const float* __restrict__ h, const int* __restrict__ gids,
                          float* __restrict__ gsum, int nn)
{
  int j = threadIdx.x & 63;
  int slot = threadIdx.x >> 6;
  int base = blockIdx.x * 64;
  float acc = 0.f;
  int cur = -1;
  for (int i = 0; i < 16; ++i) {
    int node = base + slot + i * 4;
    if (node < nn) {
      int g = gids[node];
      if (g != cur) {
        if (cur >= 0) unsafeAtomicAdd(&gsum[cur * 64 + j], acc);
        cur = g; acc = 0.f;
      }
      acc += h[(size_t)node * 64 + j];
    }
  }
  if (cur >= 0) unsafeAtomicAdd(&gsum[cur * 64 + j], acc);
}

// ---------------- g = gsum @ Wr + br ----------------
__global__ void k_gproj(const float* __restrict__ gsum, const float* __restrict__ Wr,
                        const float* __restrict__ br, float* __restrict__ g)
{
  int gi = blockIdx.x;
  int j = threadIdx.x;
  float acc = br[j];
  for (int k = 0; k < 64; ++k)
    acc = fmaf(gsum[gi * 64 + k], Wr[k * 64 + j], acc);
  g[gi * 64 + j] = acc;
}

// -------- node update: h[n] += LN(MLPu([h,agg])) + LN(MLPg([h,g[gid]]))
// 2-way split like k_unary; both lanes keep both output chunks (butterfly),
// LN computed redundantly; lane q stores chunk q of the residual.
__global__ void __launch_bounds__(256, 2) k_update(
    float* __restrict__ h, const float* __restrict__ agg,
    const float* __restrict__ gvec, const int* __restrict__ gids,
    const float* __restrict__ Wu1_, const float* __restrict__ bu1_,
    const float* __restrict__ Wu2_, const float* __restrict__ bu2_,
    const float* __restrict__ Wg1_, const float* __restrict__ bg1_,
    const float* __restrict__ Wg2_, const float* __restrict__ bg2_,
    const float* __restrict__ lnw_, const float* __restrict__ lnb_,
    int nn)
{
  __shared__ float tl[256 * 33];
  const int tid = threadIdx.x;
  const int lane = tid & 63;
  const int q = lane >> 5;
  const int n = blockIdx.x * 128 + (tid >> 6) * 32 + (lane & 31);
  if (n >= nn) return;
  const float* Wu1 = vpin(Wu1_); const float* bu1 = vpin(bu1_);
  const float* Wu2 = vpin(Wu2_); const float* bu2 = vpin(bu2_);
  const float* Wg1 = vpin(Wg1_); const float* bg1 = vpin(bg1_);
  const float* Wg2 = vpin(Wg2_); const float* bg2 = vpin(bg2_);
  const float* lnw = vpin(lnw_); const float* lnb = vpin(lnb_);

  const float4* hx = (const float4*)(h + (size_t)n * E);
  const float4* ax = (const float4*)(agg + (size_t)n * E);
  const int gid = gids[n];
  const float4* gx = (const float4*)(gvec + (size_t)gid * E);
  float* tme = &tl[tid * 33];

  float nxt[2][32], gm[2][32];

  // ================= MLPu: x = [h, agg] =================
  {
    float acc[32];
    load32(acc, bu1 + q * 32);
    const float* wrow = Wu1 + q * 32;     // row stride E
    #pragma unroll 2
    for (int k4 = 0; k4 < 16; ++k4) {
      float4 xv = hx[k4];
      fma32(acc, xv.x, wrow);
      fma32(acc, xv.y, wrow + E);
      fma32(acc, xv.z, wrow + 2 * E);
      fma32(acc, xv.w, wrow + 3 * E);
      wrow += 4 * E;
    }
    #pragma unroll 2
    for (int k4 = 0; k4 < 16; ++k4) {
      float4 xv = ax[k4];
      fma32(acc, xv.x, wrow);
      fma32(acc, xv.y, wrow + E);
      fma32(acc, xv.z, wrow + 2 * E);
      fma32(acc, xv.w, wrow + 3 * E);
      wrow += 4 * E;
    }
    #pragma unroll
    for (int i = 0; i < 32; ++i) tme[i] = fmaxf(acc[i], 0.f);
  }
  #pragma unroll
  for (int c = 0; c < 2; ++c) {           // fully unrolled: nxt[c] static
    float o[32];
    #pragma unroll
    for (int i = 0; i < 32; ++i) o[i] = 0.f;
    const float* w2r = Wu2 + (q * 32) * E + c * 32;
    #pragma unroll 2
    for (int k = 0; k < 32; ++k) {
      float tk = tme[k];
      fma32(o, tk, w2r);
      w2r += E;
    }
    const float4* bp = (const float4*)(bu2 + c * 32);
    #pragma unroll
    for (int i = 0; i < 8; ++i) {
      float4 bv = bp[i];
      nxt[c][4*i+0] = o[4*i+0] + __shfl_xor(o[4*i+0], 32, 64) + bv.x;
      nxt[c][4*i+1] = o[4*i+1] + __shfl_xor(o[4*i+1], 32, 64) + bv.y;
      nxt[c][4*i+2] = o[4*i+2] + __shfl_xor(o[4*i+2], 32, 64) + bv.z;
      nxt[c][4*i+3] = o[4*i+3] + __shfl_xor(o[4*i+3], 32, 64) + bv.w;
    }
  }
  { // LN(nxt)
    float mu = 0.f;
    #pragma unroll
    for (int c = 0; c < 2; ++c)
      #pragma unroll
      for (int i = 0; i < 32; ++i) mu += nxt[c][i];
    mu *= (1.f / E);
    float var = 0.f;
    #pragma unroll
    for (int c = 0; c < 2; ++c)
      #pragma unroll
      for (int i = 0; i < 32; ++i) { float dm = nxt[c][i] - mu; var += dm * dm; }
    var *= (1.f / E);
    float rs = rsqrtf(var + 1e-5f);
    #pragma unroll
    for (int c = 0; c < 2; ++c) {
      const float4* lw = (const float4*)(lnw + c * 32);
      const float4* lb = (const float4*)(lnb + c * 32);
      #pragma unroll
      for (int i = 0; i < 8; ++i) {
        float4 wv = lw[i], bv = lb[i];
        nxt[c][4*i+0] = (nxt[c][4*i+0] - mu) * rs * wv.x + bv.x;
        nxt[c][4*i+1] = (nxt[c][4*i+1] - mu) * rs * wv.y + bv.y;
        nxt[c][4*i+2] = (nxt[c][4*i+2] - mu) * rs * wv.z + bv.z;
        nxt[c][4*i+3] = (nxt[c][4*i+3] - mu) * rs * wv.w + bv.w;
      }
    }
  }

  // ================= MLPg: x = [h, g[gid]] =================
  {
    float acc[32];
    load32(acc, bg1 + q * 32);
    const float* wrow = Wg1 + q * 32;
    #pragma unroll 2
    for (int k4 = 0; k4 < 16; ++k4) {
      float4 xv = hx[k4];
      fma32(acc, xv.x, wrow);
      fma32(acc, xv.y, wrow + E);
      fma32(acc, xv.z, wrow + 2 * E);
      fma32(acc, xv.w, wrow + 3 * E);
      wrow += 4 * E;
    }
    #pragma unroll 2
    for (int k4 = 0; k4 < 16; ++k4) {
      float4 xv = gx[k4];
      fma32(acc, xv.x, wrow);
      fma32(acc, xv.y, wrow + E);
      fma32(acc, xv.z, wrow + 2 * E);
      fma32(acc, xv.w, wrow + 3 * E);
      wrow += 4 * E;
    }
    #pragma unroll
    for (int i = 0; i < 32; ++i) tme[i] = fmaxf(acc[i], 0.f);
  }
  #pragma unroll
  for (int c = 0; c < 2; ++c) {
    float o[32];
    #pragma unroll
    for (int i = 0; i < 32; ++i) o[i] = 0.f;
    const float* w2r = Wg2 + (q * 32) * E + c * 32;
    #pragma unroll 2
    for (int k = 0; k < 32; ++k) {
      float tk = tme[k];
      fma32(o, tk, w2r);
      w2r += E;
    }
    const float4* bp = (const float4*)(bg2 + c * 32);
    #pragma unroll
    for (int i = 0; i < 8; ++i) {
      float4 bv = bp[i];
      gm[c][4*i+0] = o[4*i+0] + __shfl_xor(o[4*i+0], 32, 64) + bv.x;
      gm[c][4*i+1] = o[4*i+1] + __shfl_xor(o[4*i+1], 32, 64) + bv.y;
      gm[c][4*i+2] = o[4*i+2] + __shfl_xor(o[4*i+2], 32, 64) + bv.z;
      gm[c][4*i+3] = o[4*i+3] + __shfl_xor(o[4*i+3], 32, 64) + bv.w;
    }
  }
  { // LN(gm)
    float mu = 0.f;
    #pragma unroll
    for (int c = 0; c < 2; ++c)
      #pragma unroll
      for (int i = 0; i < 32; ++i) mu += gm[c][i];
    mu *= (1.f / E);
    float var = 0.f;
    #pragma unroll
    for (int c = 0; c < 2; ++c)
      #pragma unroll
      for (int i = 0; i < 32; ++i) { float dm = gm[c][i] - mu; var += dm * dm; }
    var *= (1.f / E);
    float rs = rsqrtf(var + 1e-5f);
    #pragma unroll
    for (int c = 0; c < 2; ++c) {
      const float4* lw = (const float4*)(lnw + c * 32);
      const float4* lb = (const float4*)(lnb + c * 32);
      #pragma unroll
      for (int i = 0; i < 8; ++i) {
        float4 wv = lw[i], bv = lb[i];
        gm[c][4*i+0] = (gm[c][4*i+0] - mu) * rs * wv.x + bv.x;
        gm[c][4*i+1] = (gm[c][4*i+1] - mu) * rs * wv.y + bv.y;
        gm[c][4*i+2] = (gm[c][4*i+2] - mu) * rs * wv.z + bv.z;
        gm[c][4*i+3] = (gm[c][4*i+3] - mu) * rs * wv.w + bv.w;
      }
    }
  }

  // residual: lane q stores its chunk (select via cndmask, no dynamic index)
  {
    float4* hw = (float4*)(h + (size_t)n * E + q * 32);
    const float4* hr = (const float4*)(h + (size_t)n * E + q * 32);
    #pragma unroll
    for (int i = 0; i < 8; ++i) {
      float4 hv = hr[i];
      float a0 = (q == 0) ? (nxt[0][4*i+0] + gm[0][4*i+0]) : (nxt[1][4*i+0] + gm[1][4*i+0]);
      float a1 = (q == 0) ? (nxt[0][4*i+1] + gm[0][4*i+1]) : (nxt[1][4*i+1] + gm[1][4*i+1]);
      float a2 = (q == 0) ? (nxt[0][4*i+2] + gm[0][4*i+2]) : (nxt[1][4*i+2] + gm[1][4*i+2]);
      float a3 = (q == 0) ? (nxt[0][4*i+3] + gm[0][4*i+3]) : (nxt[1][4*i+3] + gm[1][4*i+3]);
      hw[i] = make_float4(hv.x + a0, hv.y + a1, hv.z + a2, hv.w + a3);
    }
  }
}

extern "C" void kernel_launch(void* const* d_in, const int* in_sizes, int n_in,
                              void* d_out, int out_size, void* d_ws, size_t ws_size,
                              hipStream_t stream) {
  (void)n_in; (void)out_size; (void)ws_size;
  const int*   rel_u = (const int*)d_in[0];
  const int*   rel_e = (const int*)d_in[1];
  const int*   gids  = (const int*)d_in[2];
  const float* Wm1_u = (const float*)d_in[4];
  const float* bm1_u = (const float*)d_in[5];
  const float* Wm2_u = (const float*)d_in[6];
  const float* bm2_u = (const float*)d_in[7];
  const float* Wm1_e = (const float*)d_in[8];
  const float* bm1_e = (const float*)d_in[9];
  const float* Wm2_e = (const float*)d_in[10];
  const float* bm2_e = (const float*)d_in[11];
  const float* Wu1   = (const float*)d_in[12];
  const float* bu1   = (const float*)d_in[13];
  const float* Wu2   = (const float*)d_in[14];
  const float* bu2   = (const float*)d_in[15];
  const float* lnw   = (const float*)d_in[16];
  const float* lnb   = (const float*)d_in[17];
  const float* Wr    = (const float*)d_in[18];
  const float* br    = (const float*)d_in[19];
  const float* Wg1   = (const float*)d_in[20];
  const float* bg1   = (const float*)d_in[21];
  const float* Wg2   = (const float*)d_in[22];
  const float* bg2   = (const float*)d_in[23];

  const int MU_ = in_sizes[0];          // 100000
  const int ME_ = in_sizes[1] / 2;      // 200000
  const int NN  = in_sizes[2];          // 50000
  const int GN  = 100;
  const int M   = MU_ + 2 * ME_;        // 500000 message slots

  float* h      = (float*)d_out;
  float* agg    = (float*)d_ws;                          // [N*E]
  float* gsum   = agg + (size_t)NN * E;                  // [G*E]
  float* g      = gsum + (size_t)GN * E;                 // [G*E]
  float* msgbuf = g + (size_t)GN * E;                    // [M*E]
  int*   cnt    = (int*)(msgbuf + (size_t)M * E);        // [N]
  int*   startp = cnt + NN;                              // [N+1]
  int*   cursor = startp + NN + 1;                       // [N]
  int*   idxl   = cursor + NN;                           // [M]

  {
    int n4 = NN * E / 4;
    k_zero<<<(n4 + 255) / 256, 256, 0, stream>>>((float4*)h, n4);
  }
  {
    int n4 = NN / 4;
    k_zero<<<(n4 + 255) / 256, 256, 0, stream>>>((float4*)cnt, n4);
  }
  k_count<<<(M + 255) / 256, 256, 0, stream>>>(rel_u, rel_e, cnt, MU_, M);
  k_scan<<<1, 1024, 0, stream>>>(cnt, startp, NN, M);
  k_copyint<<<(NN + 255) / 256, 256, 0, stream>>>(startp, cursor, NN);
  k_fill<<<(M + 255) / 256, 256, 0, stream>>>(rel_u, rel_e, cursor, idxl, MU_, M);

  for (int l = 0; l < 4; ++l) {
    {
      int n4 = GN * E / 4;
      k_zero<<<(n4 + 255) / 256, 256, 0, stream>>>((float4*)gsum, n4);
    }
    k_unary<<<(MU_ + 127) / 128, 256, 0, stream>>>(
        rel_u, h, Wm1_u, bm1_u, Wm2_u, bm2_u, msgbuf, MU_);
    k_edge<<<(ME_ + 63) / 64, 256, 0, stream>>>(
        rel_e, h, Wm1_e, bm1_e, Wm2_e, bm2_e, msgbuf, MU_, ME_);
    k_gather<<<(NN + 3) / 4, 256, 0, stream>>>(msgbuf, idxl, startp, agg, NN);
    k_readout<<<(NN + 63) / 64, 256, 0, stream>>>(h, gids, gsum, NN);
    k_gproj<<<GN, 64, 0, stream>>>(gsum, Wr, br, g);
    k_update<<<(NN + 127) / 128, 256, 0, stream>>>(
        h, agg, g, gids,
        Wu1, bu1, Wu2, bu2, Wg1, bg1, Wg2, bg2, lnw, lnb, NN);
  }
}

// Round 4
// 1584.108 us; speedup vs baseline: 3.3683x; 3.3683x over previous
//
#include <hip/hip_runtime.h>

// Round 4: wave-level k/output split for all MLP kernels.
//  - Weight addresses depend only on kernel args + readfirstlane(wave id)
//    -> provably wave-uniform -> scalar-pipe s_load broadcast (no VMEM, no LDS).
//  - Per-thread live state = acc[32] only -> no spills, no launch_bounds caps.
//  - t tiles staged in LDS with b128-friendly strides (132/68 words), one
//    barrier between MLP layers. 4 blocks/CU (16 waves/CU) target occupancy.

#define E 64
#define TWO_E 128

// acc[0..31] += xu * w[0..31], w wave-uniform (scalar loads)
__device__ __forceinline__ void sfma32(float (&acc)[32], float xu, const float* w) {
  #pragma unroll
  for (int i = 0; i < 32; ++i) acc[i] = fmaf(xu, w[i], acc[i]);
}

// ---------------- zero ----------------
__global__ void k_zero(float4* __restrict__ p, int n4) {
  int i = blockIdx.x * blockDim.x + threadIdx.x;
  if (i < n4) p[i] = make_float4(0.f, 0.f, 0.f, 0.f);
}

// ---------------- CSR build (once per launch) ----------------
__global__ void k_count(const int* __restrict__ rel_u, const int* __restrict__ rel_e,
                        int* __restrict__ cnt, int mu, int M) {
  int m = blockIdx.x * blockDim.x + threadIdx.x;
  if (m >= M) return;
  int d = (m < mu) ? rel_u[m] : rel_e[m - mu];
  atomicAdd(&cnt[d], 1);
}

__global__ void __launch_bounds__(1024) k_scan(const int* __restrict__ cnt,
                                               int* __restrict__ startp, int nn, int M) {
  __shared__ int ls[1024];
  int t = threadIdx.x;
  const int C = 49;
  int c0 = t * C, c1 = min(c0 + C, nn);
  int s = 0;
  for (int i = c0; i < c1; ++i) s += cnt[i];
  ls[t] = s;
  __syncthreads();
  for (int off = 1; off < 1024; off <<= 1) {
    int v = (t >= off) ? ls[t - off] : 0;
    __syncthreads();
    ls[t] += v;
    __syncthreads();
  }
  int run = (t > 0) ? ls[t - 1] : 0;
  for (int i = c0; i < c1; ++i) { startp[i] = run; run += cnt[i]; }
  if (t == 1023) startp[nn] = M;
}

__global__ void k_copyint(const int* __restrict__ a, int* __restrict__ b, int n) {
  int i = blockIdx.x * blockDim.x + threadIdx.x;
  if (i < n) b[i] = a[i];
}

__global__ void k_fill(const int* __restrict__ rel_u, const int* __restrict__ rel_e,
                       int* __restrict__ cursor, int* __restrict__ idx, int mu, int M) {
  int m = blockIdx.x * blockDim.x + threadIdx.x;
  if (m >= M) return;
  int d = (m < mu) ? rel_u[m] : rel_e[m - mu];
  int p = atomicAdd(&cursor[d], 1);
  idx[p] = m;
}

// -------- unary messages: block = 4 waves over 128 atoms.
// Wave pair g handles atoms[g*64 + lane]; within pair, wave q owns hidden
// half q (layer 1) and output chunk q (layer 2). Weights wave-uniform.
__global__ void __launch_bounds__(256) k_unary(
    const int* __restrict__ rel_u, const float* __restrict__ h,
    const float* __restrict__ W1, const float* __restrict__ b1,
    const float* __restrict__ W2, const float* __restrict__ b2,
    float* __restrict__ msgbuf, int mu)
{
  __shared__ __align__(16) float tl[128 * 68];   // 34,816 B
  const int tid = threadIdx.x;
  const int lane = tid & 63;
  const int wq = __builtin_amdgcn_readfirstlane(tid >> 6);  // 0..3, SGPR
  const int g = wq >> 1, q = wq & 1;
  const int a = blockIdx.x * 128 + g * 64 + lane;
  const bool valid = (a < mu);
  const int ac = valid ? a : (mu - 1);
  const int idx = rel_u[ac];
  const float4* x4 = (const float4*)(h + (size_t)idx * E);
  const int nl = g * 64 + lane;

  // layer 1: hidden[q*32 .. q*32+32)
  float acc[32];
  {
    const float* bp = b1 + q * 32;
    #pragma unroll
    for (int i = 0; i < 32; ++i) acc[i] = bp[i];
  }
  {
    const float* w = W1 + q * 32;          // row stride E
    #pragma unroll 2
    for (int k4 = 0; k4 < 16; ++k4) {
      float4 xv = x4[k4];
      sfma32(acc, xv.x, w);
      sfma32(acc, xv.y, w + E);
      sfma32(acc, xv.z, w + 2 * E);
      sfma32(acc, xv.w, w + 3 * E);
      w += 4 * E;
    }
  }
  {
    float4* trow = (float4*)&tl[nl * 68 + q * 32];
    #pragma unroll
    for (int i = 0; i < 8; ++i)
      trow[i] = make_float4(fmaxf(acc[4*i], 0.f), fmaxf(acc[4*i+1], 0.f),
                            fmaxf(acc[4*i+2], 0.f), fmaxf(acc[4*i+3], 0.f));
  }
  __syncthreads();

  // layer 2: output chunk q over all 64 hidden
  float o[32];
  {
    const float* bp = b2 + q * 32;
    #pragma unroll
    for (int i = 0; i < 32; ++i) o[i] = bp[i];
  }
  {
    const float4* tr = (const float4*)&tl[nl * 68];
    const float* w = W2 + q * 32;          // row stride E
    #pragma unroll 2
    for (int kk = 0; kk < 16; ++kk) {
      float4 tv = tr[kk];
      sfma32(o, tv.x, w);
      sfma32(o, tv.y, w + E);
      sfma32(o, tv.z, w + 2 * E);
      sfma32(o, tv.w, w + 3 * E);
      w += 4 * E;
    }
  }
  if (valid) {
    float4* mp = (float4*)(msgbuf + (size_t)a * E + q * 32);
    #pragma unroll
    for (int i = 0; i < 8; ++i)
      mp[i] = make_float4(o[4*i], o[4*i+1], o[4*i+2], o[4*i+3]);
  }
}

// -------- edge messages: block = 4 waves over 64 edges (lane = edge).
// Wave wq owns hidden quarter wq (layer 1) and output chunk wq (layer 2).
// out chunks 0,1 -> slot mu+2e (->s); chunks 2,3 -> slot mu+2e+1 (->d).
__global__ void __launch_bounds__(256) k_edge(
    const int* __restrict__ rel_e, const float* __restrict__ h,
    const float* __restrict__ W1, const float* __restrict__ b1,
    const float* __restrict__ W2, const float* __restrict__ b2,
    float* __restrict__ msgbuf, int mu, int me)
{
  __shared__ __align__(16) float tl[64 * 132];   // 33,792 B
  const int tid = threadIdx.x;
  const int lane = tid & 63;
  const int wq = __builtin_amdgcn_readfirstlane(tid >> 6);  // 0..3, SGPR
  const int e = blockIdx.x * 64 + lane;
  const bool valid = (e < me);
  const int ec = valid ? e : (me - 1);
  const int s = rel_e[2 * ec], d = rel_e[2 * ec + 1];
  const float4* xs4 = (const float4*)(h + (size_t)s * E);
  const float4* xd4 = (const float4*)(h + (size_t)d * E);

  // layer 1: hidden[wq*32 .. wq*32+32) from 128-wide [h[s], h[d]]
  float acc[32];
  {
    const float* bp = b1 + wq * 32;
    #pragma unroll
    for (int i = 0; i < 32; ++i) acc[i] = bp[i];
  }
  {
    const float* w = W1 + wq * 32;         // row stride TWO_E
    #pragma unroll 2
    for (int k4 = 0; k4 < 16; ++k4) {
      float4 xv = xs4[k4];
      sfma32(acc, xv.x, w);
      sfma32(acc, xv.y, w + TWO_E);
      sfma32(acc, xv.z, w + 2 * TWO_E);
      sfma32(acc, xv.w, w + 3 * TWO_E);
      w += 4 * TWO_E;
    }
    #pragma unroll 2
    for (int k4 = 0; k4 < 16; ++k4) {
      float4 xv = xd4[k4];
      sfma32(acc, xv.x, w);
      sfma32(acc, xv.y, w + TWO_E);
      sfma32(acc, xv.z, w + 2 * TWO_E);
      sfma32(acc, xv.w, w + 3 * TWO_E);
      w += 4 * TWO_E;
    }
  }
  {
    float4* trow = (float4*)&tl[lane * 132 + wq * 32];
    #pragma unroll
    for (int i = 0; i < 8; ++i)
      trow[i] = make_float4(fmaxf(acc[4*i], 0.f), fmaxf(acc[4*i+1], 0.f),
                            fmaxf(acc[4*i+2], 0.f), fmaxf(acc[4*i+3], 0.f));
  }
  __syncthreads();

  // layer 2: output chunk wq over all 128 hidden
  float o[32];
  {
    const float* bp = b2 + wq * 32;
    #pragma unroll
    for (int i = 0; i < 32; ++i) o[i] = bp[i];
  }
  {
    const float4* tr = (const float4*)&tl[lane * 132];
    const float* w = W2 + wq * 32;         // row stride TWO_E
    #pragma unroll 2
    for (int kk = 0; kk < 32; ++kk) {
      float4 tv = tr[kk];
      sfma32(o, tv.x, w);
      sfma32(o, tv.y, w + TWO_E);
      sfma32(o, tv.z, w + 2 * TWO_E);
      sfma32(o, tv.w, w + 3 * TWO_E);
      w += 4 * TWO_E;
    }
  }
  if (valid) {
    size_t slot = (size_t)mu + 2 * (size_t)e + (wq >> 1);
    float4* mp = (float4*)(msgbuf + slot * E + (wq & 1) * 32);
    #pragma unroll
    for (int i = 0; i < 8; ++i)
      mp[i] = make_float4(o[4*i], o[4*i+1], o[4*i+2], o[4*i+3]);
  }
}

// ---------------- gather: agg[n] = sum msgbuf[idx[start[n]..start[n+1])] ----
__global__ void __launch_bounds__(256) k_gather(
    const float* __restrict__ msgbuf, const int* __restrict__ idx,
    const int* __restrict__ startp, float* __restrict__ agg, int nn)
{
  int wave = threadIdx.x >> 6;
  int j = threadIdx.x & 63;
  int n = blockIdx.x * 4 + wave;
  if (n >= nn) return;
  int s0 = startp[n], s1 = startp[n + 1];
  float v = 0.f;
  for (int i = s0; i < s1; ++i) {
    int m = idx[i];
    v += msgbuf[(size_t)m * E + j];
  }
  agg[(size_t)n * E + j] = v;
}

// ---------------- readout: gsum[g] = sum_{n in g} h[n] ----------------
__global__ void k_readout(const float* __restrict__ h, const int* __restrict__ gids,
                          float* __restrict__ gsum, int nn)
{
  int j = threadIdx.x & 63;
  int slot = threadIdx.x >> 6;
  int base = blockIdx.x * 64;
  float acc = 0.f;
  int cur = -1;
  for (int i = 0; i < 16; ++i) {
    int node = base + slot + i * 4;
    if (node < nn) {
      int g = gids[node];
      if (g != cur) {
        if (cur >= 0) unsafeAtomicAdd(&gsum[cur * 64 + j], acc);
        cur = g; acc = 0.f;
      }
      acc += h[(size_t)node * 64 + j];
    }
  }
  if (cur >= 0) unsafeAtomicAdd(&gsum[cur * 64 + j], acc);
}

// ---------------- g = gsum @ Wr + br ----------------
__global__ void k_gproj(const float* __restrict__ gsum, const float* __restrict__ Wr,
                        const float* __restrict__ br, float* __restrict__ g)
{
  int gi = blockIdx.x;
  int j = threadIdx.x;
  float acc = br[j];
  for (int k = 0; k < 64; ++k)
    acc = fmaf(gsum[gi * 64 + k], Wr[k * 64 + j], acc);
  g[gi * 64 + j] = acc;
}

// -------- node update: h[n] += LN(MLPu([h,agg])) + LN(MLPg([h,g[gid]]))
// Block = 4 waves over 128 nodes; wave pair g handles nodes[g*64+lane];
// wave q owns hidden half q / output chunk q. LN stats combined across the
// wave pair via small LDS array (two-pass: mean, then centered variance).
__global__ void __launch_bounds__(256) k_update(
    float* __restrict__ h, const float* __restrict__ agg,
    const float* __restrict__ gvec, const int* __restrict__ gids,
    const float* __restrict__ Wu1, const float* __restrict__ bu1,
    const float* __restrict__ Wu2, const float* __restrict__ bu2,
    const float* __restrict__ Wg1, const float* __restrict__ bg1,
    const float* __restrict__ Wg2, const float* __restrict__ bg2,
    const float* __restrict__ lnw, const float* __restrict__ lnb,
    int nn)
{
  __shared__ __align__(16) float tl[128 * 68];   // 34,816 B
  __shared__ float st[128 * 5];                  // 2,560 B (stride 5: bank-spread)
  const int tid = threadIdx.x;
  const int lane = tid & 63;
  const int wq = __builtin_amdgcn_readfirstlane(tid >> 6);
  const int g = wq >> 1, q = wq & 1;
  const int n = blockIdx.x * 128 + g * 64 + lane;
  const bool valid = (n < nn);
  const int ncl = valid ? n : (nn - 1);
  const int gid = gids[ncl];
  const float4* hx = (const float4*)(h + (size_t)ncl * E);
  const float4* ax = (const float4*)(agg + (size_t)ncl * E);
  const float4* gx = (const float4*)(gvec + (size_t)gid * E);
  const int nl = g * 64 + lane;

  float res[32];

  #pragma unroll
  for (int pass = 0; pass < 2; ++pass) {
    const float* W1 = (pass == 0) ? Wu1 : Wg1;
    const float* B1 = (pass == 0) ? bu1 : bg1;
    const float* W2 = (pass == 0) ? Wu2 : Wg2;
    const float* B2 = (pass == 0) ? bu2 : bg2;
    const float4* xb = (pass == 0) ? ax : gx;

    // layer 1: hidden half q from 128-wide [h[n], xb]
    float acc[32];
    {
      const float* bp = B1 + q * 32;
      #pragma unroll
      for (int i = 0; i < 32; ++i) acc[i] = bp[i];
    }
    {
      const float* w = W1 + q * 32;        // row stride E (out dim 64)
      #pragma unroll 2
      for (int k4 = 0; k4 < 16; ++k4) {
        float4 xv = hx[k4];
        sfma32(acc, xv.x, w);
        sfma32(acc, xv.y, w + E);
        sfma32(acc, xv.z, w + 2 * E);
        sfma32(acc, xv.w, w + 3 * E);
        w += 4 * E;
      }
      #pragma unroll 2
      for (int k4 = 0; k4 < 16; ++k4) {
        float4 xv = xb[k4];
        sfma32(acc, xv.x, w);
        sfma32(acc, xv.y, w + E);
        sfma32(acc, xv.z, w + 2 * E);
        sfma32(acc, xv.w, w + 3 * E);
        w += 4 * E;
      }
    }
    __syncthreads();                       // tl free (prev pass fully consumed)
    {
      float4* trow = (float4*)&tl[nl * 68 + q * 32];
      #pragma unroll
      for (int i = 0; i < 8; ++i)
        trow[i] = make_float4(fmaxf(acc[4*i], 0.f), fmaxf(acc[4*i+1], 0.f),
                              fmaxf(acc[4*i+2], 0.f), fmaxf(acc[4*i+3], 0.f));
    }
    __syncthreads();

    // layer 2: output chunk q over all 64 hidden
    float o[32];
    {
      const float* bp = B2 + q * 32;
      #pragma unroll
      for (int i = 0; i < 32; ++i) o[i] = bp[i];
    }
    {
      const float4* tr = (const float4*)&tl[nl * 68];
      const float* w = W2 + q * 32;
      #pragma unroll 2
      for (int kk = 0; kk < 16; ++kk) {
        float4 tv = tr[kk];
        sfma32(o, tv.x, w);
        sfma32(o, tv.y, w + E);
        sfma32(o, tv.z, w + 2 * E);
        sfma32(o, tv.w, w + 3 * E);
        w += 4 * E;
      }
    }

    // LayerNorm across the wave pair (two-pass, matches reference form)
    float s1 = 0.f;
    #pragma unroll
    for (int i = 0; i < 32; ++i) s1 += o[i];
    st[nl * 5 + q] = s1;
    __syncthreads();
    float mu = (st[nl * 5 + 0] + st[nl * 5 + 1]) * (1.f / E);
    float s2 = 0.f;
    #pragma unroll
    for (int i = 0; i < 32; ++i) { float dm = o[i] - mu; s2 += dm * dm; }
    st[nl * 5 + 2 + q] = s2;
    __syncthreads();
    float var = (st[nl * 5 + 2] + st[nl * 5 + 3]) * (1.f / E);
    float rs = rsqrtf(var + 1e-5f);
    {
      const float* lw = lnw + q * 32;
      const float* lb = lnb + q * 32;
      #pragma unroll
      for (int i = 0; i < 32; ++i) {
        float v = (o[i] - mu) * rs * lw[i] + lb[i];
        if (pass == 0) res[i] = v; else res[i] += v;
      }
    }
  }

  // residual: wave q writes chunk q of its node
  if (valid) {
    float4* hw = (float4*)(h + (size_t)n * E + q * 32);
    #pragma unroll
    for (int i = 0; i < 8; ++i) {
      float4 hv = hw[i];
      hw[i] = make_float4(hv.x + res[4*i], hv.y + res[4*i+1],
                          hv.z + res[4*i+2], hv.w + res[4*i+3]);
    }
  }
}

extern "C" void kernel_launch(void* const* d_in, const int* in_sizes, int n_in,
                              void* d_out, int out_size, void* d_ws, size_t ws_size,
                              hipStream_t stream) {
  (void)n_in; (void)out_size; (void)ws_size;
  const int*   rel_u = (const int*)d_in[0];
  const int*   rel_e = (const int*)d_in[1];
  const int*   gids  = (const int*)d_in[2];
  const float* Wm1_u = (const float*)d_in[4];
  const float* bm1_u = (const float*)d_in[5];
  const float* Wm2_u = (const float*)d_in[6];
  const float* bm2_u = (const float*)d_in[7];
  const float* Wm1_e = (const float*)d_in[8];
  const float* bm1_e = (const float*)d_in[9];
  const float* Wm2_e = (const float*)d_in[10];
  const float* bm2_e = (const float*)d_in[11];
  const float* Wu1   = (const float*)d_in[12];
  const float* bu1   = (const float*)d_in[13];
  const float* Wu2   = (const float*)d_in[14];
  const float* bu2   = (const float*)d_in[15];
  const float* lnw   = (const float*)d_in[16];
  const float* lnb   = (const float*)d_in[17];
  const float* Wr    = (const float*)d_in[18];
  const float* br    = (const float*)d_in[19];
  const float* Wg1   = (const float*)d_in[20];
  const float* bg1   = (const float*)d_in[21];
  const float* Wg2   = (const float*)d_in[22];
  const float* bg2   = (const float*)d_in[23];

  const int MU_ = in_sizes[0];          // 100000
  const int ME_ = in_sizes[1] / 2;      // 200000
  const int NN  = in_sizes[2];          // 50000
  const int GN  = 100;
  const int M   = MU_ + 2 * ME_;        // 500000 message slots

  float* h      = (float*)d_out;
  float* agg    = (float*)d_ws;                          // [N*E]
  float* gsum   = agg + (size_t)NN * E;                  // [G*E]
  float* g      = gsum + (size_t)GN * E;                 // [G*E]
  float* msgbuf = g + (size_t)GN * E;                    // [M*E]
  int*   cnt    = (int*)(msgbuf + (size_t)M * E);        // [N]
  int*   startp = cnt + NN;                              // [N+1]
  int*   cursor = startp + NN + 1;                       // [N]
  int*   idxl   = cursor + NN;                           // [M]

  {
    int n4 = NN * E / 4;
    k_zero<<<(n4 + 255) / 256, 256, 0, stream>>>((float4*)h, n4);
  }
  {
    int n4 = NN / 4;
    k_zero<<<(n4 + 255) / 256, 256, 0, stream>>>((float4*)cnt, n4);
  }
  k_count<<<(M + 255) / 256, 256, 0, stream>>>(rel_u, rel_e, cnt, MU_, M);
  k_scan<<<1, 1024, 0, stream>>>(cnt, startp, NN, M);
  k_copyint<<<(NN + 255) / 256, 256, 0, stream>>>(startp, cursor, NN);
  k_fill<<<(M + 255) / 256, 256, 0, stream>>>(rel_u, rel_e, cursor, idxl, MU_, M);

  for (int l = 0; l < 4; ++l) {
    {
      int n4 = GN * E / 4;
      k_zero<<<(n4 + 255) / 256, 256, 0, stream>>>((float4*)gsum, n4);
    }
    k_unary<<<(MU_ + 127) / 128, 256, 0, stream>>>(
        rel_u, h, Wm1_u, bm1_u, Wm2_u, bm2_u, msgbuf, MU_);
    k_edge<<<(ME_ + 63) / 64, 256, 0, stream>>>(
        rel_e, h, Wm1_e, bm1_e, Wm2_e, bm2_e, msgbuf, MU_, ME_);
    k_gather<<<(NN + 3) / 4, 256, 0, stream>>>(msgbuf, idxl, startp, agg, NN);
    k_readout<<<(NN + 63) / 64, 256, 0, stream>>>(h, gids, gsum, NN);
    k_gproj<<<GN, 64, 0, stream>>>(gsum, Wr, br, g);
    k_update<<<(NN + 127) / 128, 256, 0, stream>>>(
        h, agg, g, gids,
        Wu1, bu1, Wu2, bu2, Wg1, bg1, Wg2, bg2, lnw, lnb, NN);
  }
}